// Round 3
// baseline (459.806 us; speedup 1.0000x reference)
//
#include <hip/hip_runtime.h>
#include <hip/hip_bf16.h>
#include <stdint.h>

// dist[i,j] = ||s_i||^2 + ||t_j||^2 - 2 s_i . t_j
// prep: s -> bf16(-2*s), t -> bf16(t) into d_ws + exact f32 row norms.
// main: ZERO-LDS, ZERO-BARRIER register-dataflow MFMA GEMM.
//   Inputs are 16 MB bf16 total -> fully L2/L3-resident, so LDS staging is
//   pure overhead here (Common-mistake #7). Each wave computes an
//   independent 64x128 output tile; A/B fragments are loaded DIRECTLY from
//   global as 16B chunks (b128, 16 full 64B lines per instr). No barriers,
//   no races; compiler software-pipelines freely (m97-regime strength).
//   Block = 4 waves stacked along M (256x128 block tile), 2048 blocks,
//   XCD-chunked bijective block mapping (each XCD gets a 16x16-block
//   region: ~6 MB working set, mostly L2-local).
// Round-1/2 lessons: 256^2 8-phase LDS pipelines (m201-style) lose here —
// K=512 gives only 8 K-tiles/block, so the pipeline never reaches steady
// state and 1 resident block exposes every bubble. The 128^2 baseline won
// via multi-block TLP; this design maximizes exactly that (independent
// waves, zero sync).

typedef __attribute__((ext_vector_type(8))) short short8v;   // 8 bf16 (4 VGPRs)
typedef __attribute__((ext_vector_type(4))) float f32x4;     // 4 fp32 acc

static __device__ __forceinline__ unsigned short f32_to_bf16_rne(float f) {
    unsigned int u = __float_as_uint(f);
    unsigned int lsb = (u >> 16) & 1u;
    u += 0x7fffu + lsb;
    return (unsigned short)(u >> 16);
}

// One wave per row (D must be 512): 8 f32/lane, norm + scaled bf16 conversion.
__global__ __launch_bounds__(256) void prep_kernel(const float* __restrict__ x,
                                                   unsigned short* __restrict__ xb,
                                                   float* __restrict__ nrm,
                                                   float scale) {
    const int tid  = threadIdx.x;
    const int wid  = tid >> 6;
    const int lane = tid & 63;
    const int row  = blockIdx.x * 4 + wid;
    const float* xr = x + (size_t)row * 512;

    float4 v0 = ((const float4*)xr)[lane * 2 + 0];
    float4 v1 = ((const float4*)xr)[lane * 2 + 1];

    float ss = v0.x * v0.x + v0.y * v0.y + v0.z * v0.z + v0.w * v0.w
             + v1.x * v1.x + v1.y * v1.y + v1.z * v1.z + v1.w * v1.w;
#pragma unroll
    for (int off = 32; off > 0; off >>= 1) ss += __shfl_down(ss, off, 64);
    if (lane == 0) nrm[row] = ss;

    unsigned short u[8];
    float vals[8] = {v0.x, v0.y, v0.z, v0.w, v1.x, v1.y, v1.z, v1.w};
#pragma unroll
    for (int e = 0; e < 8; ++e) u[e] = f32_to_bf16_rne(vals[e] * scale);
    unsigned int w0 = (unsigned)u[0] | ((unsigned)u[1] << 16);
    unsigned int w1 = (unsigned)u[2] | ((unsigned)u[3] << 16);
    unsigned int w2 = (unsigned)u[4] | ((unsigned)u[5] << 16);
    unsigned int w3 = (unsigned)u[6] | ((unsigned)u[7] << 16);
    uint4 pk = make_uint4(w0, w1, w2, w3);
    ((uint4*)(xb + (size_t)row * 512))[lane] = pk;
}

#define BM 256   // block M: 4 waves x 64
#define BN 128   // block N: each wave spans full 128

// Fragment sourcing (de-swizzled from the verified LDS kernel): for MFMA
// 16x16x32_bf16, lane (quad,r) of the A-frag for m-subtile im at K-step t
// holds the 16B chunk at row (gm+im*16+r), element offset t*32 + quad*8.
// Same for B with rows (gn+in*16+r). Epilogue C/D layout unchanged:
// col = lane&15, row = quad*4 + reg.

__global__ __launch_bounds__(256, 2) void dist_mfma(const unsigned short* __restrict__ sb,
                                                    const unsigned short* __restrict__ tb,
                                                    const float* __restrict__ ssq,
                                                    const float* __restrict__ tsq,
                                                    float* __restrict__ out,
                                                    int N, int Q, int D) {
    const int tid  = threadIdx.x;
    const int wid  = tid >> 6;
    const int lane = tid & 63;
    const int quad = lane >> 4;
    const int r    = lane & 15;

    // block -> (bm,bn): XCD-chunked bijective mapping for the 8192^2 shape
    // (nBm=32, nBn=64 -> 8 chunks of 16x16 blocks, one per XCD; each XCD's
    // region reads A 4 MB + B 2 MB). Fallback: linear.
    const int bid = blockIdx.x;
    const int nBm = N / BM, nBn = Q / BN;
    int bm, bn;
    if (nBm == 32 && nBn == 64) {
        const int c = bid & 7;        // hw XCD round-robin -> chunk id
        const int w = bid >> 3;       // 0..255 within chunk
        bm = (c >> 2) * 16 + (w >> 4);
        bn = (c & 3) * 16 + (w & 15);
    } else {
        bm = bid / nBn;
        bn = bid - bm * nBn;
    }

    const int gm = bm * BM + wid * 64;
    const int gn = bn * BN;

    // Per-frag base pointers: +quad*8 folded in; K-step t adds t*32 elems
    // (t*64 B -> fits the 13-bit signed imm offset, so the unrolled loop is
    // pure global_load_dwordx4 ... offset:t*64 off one address register).
    const unsigned short* aP[4];
    const unsigned short* bP[8];
#pragma unroll
    for (int im = 0; im < 4; ++im)
        aP[im] = sb + (size_t)(gm + im * 16 + r) * 512 + quad * 8;
#pragma unroll
    for (int in = 0; in < 8; ++in)
        bP[in] = tb + (size_t)(gn + in * 16 + r) * 512 + quad * 8;

    f32x4 acc[4][8];
#pragma unroll
    for (int a = 0; a < 4; ++a)
#pragma unroll
        for (int b = 0; b < 8; ++b) acc[a][b] = (f32x4){0.f, 0.f, 0.f, 0.f};

    // K loop: 16 iters x K=32. unroll 4 gives the scheduler a 48-load /
    // 128-MFMA window to hoist next-iter loads under current MFMAs without
    // blowing the 256-VGPR budget.
#pragma unroll 4
    for (int t = 0; t < 16; ++t) {
        short8v aF[4], bF[8];
#pragma unroll
        for (int im = 0; im < 4; ++im)
            aF[im] = *(const short8v*)(aP[im] + t * 32);
#pragma unroll
        for (int in = 0; in < 8; ++in)
            bF[in] = *(const short8v*)(bP[in] + t * 32);
#pragma unroll
        for (int im = 0; im < 4; ++im)
#pragma unroll
            for (int in = 0; in < 8; ++in)
                acc[im][in] = __builtin_amdgcn_mfma_f32_16x16x32_bf16(
                    aF[im], bF[in], acc[im][in], 0, 0, 0);
    }

    // epilogue: C/D layout col = lane&15, row = quad*4 + reg. Nontemporal
    // stores: keep L2/L3-resident bf16 inputs from being evicted by the
    // 268 MB output stream; stores drain across wave retirement.
    float tq[8];
#pragma unroll
    for (int in = 0; in < 8; ++in) tq[in] = tsq[gn + in * 16 + r];
#pragma unroll
    for (int im = 0; im < 4; ++im) {
#pragma unroll
        for (int j = 0; j < 4; ++j) {
            const int i = gm + im * 16 + quad * 4 + j;
            const float sv = ssq[i];
            float* orow = out + (size_t)i * (size_t)Q + gn;
#pragma unroll
            for (int in = 0; in < 8; ++in)
                __builtin_nontemporal_store(sv + tq[in] + acc[im][in][j],
                                            &orow[in * 16 + r]);
        }
    }
}

// Correctness fallback if d_ws is too small for the bf16 copies or shapes
// don't fit the tiled path.
__global__ void dist_fallback(const float* __restrict__ s, const float* __restrict__ t,
                              float* __restrict__ out, int N, int Q, int D) {
    __shared__ float ls[16][17], lt[16][17];
    const int tj = threadIdx.x, ti = threadIdx.y;
    const int i = blockIdx.y * 16 + ti, j = blockIdx.x * 16 + tj;
    float cross = 0.f, ssq = 0.f, tsq = 0.f;
    for (int k0 = 0; k0 < D; k0 += 16) {
        __syncthreads();
        ls[ti][tj] = s[(size_t)(blockIdx.y * 16 + ti) * D + k0 + tj];
        lt[ti][tj] = t[(size_t)(blockIdx.x * 16 + ti) * D + k0 + tj];
        __syncthreads();
#pragma unroll
        for (int kk = 0; kk < 16; ++kk) {
            float a = ls[ti][kk], b = lt[tj][kk];
            cross += a * b; ssq += a * a; tsq += b * b;
        }
    }
    out[(size_t)i * Q + j] = ssq + tsq - 2.f * cross;
}

extern "C" void kernel_launch(void* const* d_in, const int* in_sizes, int n_in,
                              void* d_out, int out_size, void* d_ws, size_t ws_size,
                              hipStream_t stream) {
    const float* s = (const float*)d_in[0];
    const float* t = (const float*)d_in[1];
    float* out = (float*)d_out;
    const int D = 512;
    const int N = in_sizes[0] / D;  // 8192
    const int Q = in_sizes[1] / D;  // 8192

    const size_t need = ((size_t)N + (size_t)Q) * D * sizeof(unsigned short)
                      + ((size_t)N + (size_t)Q) * sizeof(float);

    if (ws_size >= need && D == 512 && (N % BM) == 0 && (Q % BN) == 0) {
        unsigned short* sb = (unsigned short*)d_ws;
        unsigned short* tb = sb + (size_t)N * D;
        float* ssq = (float*)(tb + (size_t)Q * D);
        float* tsq = ssq + N;
        prep_kernel<<<N / 4, 256, 0, stream>>>(s, sb, ssq, -2.0f);
        prep_kernel<<<Q / 4, 256, 0, stream>>>(t, tb, tsq, 1.0f);
        const int blocks = (N / BM) * (Q / BN);
        dist_mfma<<<blocks, 256, 0, stream>>>(sb, tb, ssq, tsq, out, N, Q, D);
    } else {
        dim3 g(Q / 16, N / 16), b(16, 16);
        dist_fallback<<<g, b, 0, stream>>>(s, t, out, N, Q, D);
    }
}

// Round 4
// 446.360 us; speedup vs baseline: 1.0301x; 1.0301x over previous
//
#include <hip/hip_runtime.h>
#include <hip/hip_bf16.h>
#include <stdint.h>

// dist[i,j] = ||s_i||^2 + ||t_j||^2 - 2 s_i . t_j
// prep: s -> bf16(-2*s), t -> bf16(t) into d_ws + exact f32 row norms.
// main: PERSISTENT A-PANEL MFMA GEMM. One block per CU (grid = (N/128)*4 =
// 256), 4 waves. A-panel (128 rows x K=512 = 128 KB) staged into LDS ONCE,
// then 32 B-tiles (64 cols x K) streamed through a 3-slot ring (24 KB).
// Amortizes per-block fixed cost over 256 K-iters (r0's 128^2 design had 8),
// cuts A L2 traffic 537->33 MB. One barrier/iter (3-deep ring makes the
// stage(u+2) slot's last readers >=1 barrier old); vmcnt(2) certifies tile u
// while keeping the newest prefetch in flight (never 0 mid-loop).
// Fragment formulas + 16B-chunk XOR swizzle (slot = chunk ^ (row&7), 2-way
// max = free) carried unchanged from the verified r0 kernel.
// Round-3 lesson: zero-LDS direct-global is latency-bound (MfmaUtil 12%,
// occupancy-capped grid); staging via global_load_lds + LDS reuse is the
// right regime for L2/L3-resident inputs at this shape.

typedef __attribute__((ext_vector_type(8))) short short8v;   // 8 bf16 (4 VGPRs)
typedef __attribute__((ext_vector_type(4))) float f32x4;     // 4 fp32 acc

static __device__ __forceinline__ unsigned short f32_to_bf16_rne(float f) {
    unsigned int u = __float_as_uint(f);
    unsigned int lsb = (u >> 16) & 1u;
    u += 0x7fffu + lsb;
    return (unsigned short)(u >> 16);
}

static __device__ __forceinline__ void async_load16(const void* g, void* l) {
    __builtin_amdgcn_global_load_lds(
        (const __attribute__((address_space(1))) void*)g,
        (__attribute__((address_space(3))) void*)l,
        16, 0, 0);
}

// One wave per row (D must be 512): 8 f32/lane, norm + scaled bf16 conversion.
__global__ __launch_bounds__(256) void prep_kernel(const float* __restrict__ x,
                                                   unsigned short* __restrict__ xb,
                                                   float* __restrict__ nrm,
                                                   float scale) {
    const int tid  = threadIdx.x;
    const int wid  = tid >> 6;
    const int lane = tid & 63;
    const int row  = blockIdx.x * 4 + wid;
    const float* xr = x + (size_t)row * 512;

    float4 v0 = ((const float4*)xr)[lane * 2 + 0];
    float4 v1 = ((const float4*)xr)[lane * 2 + 1];

    float ss = v0.x * v0.x + v0.y * v0.y + v0.z * v0.z + v0.w * v0.w
             + v1.x * v1.x + v1.y * v1.y + v1.z * v1.z + v1.w * v1.w;
#pragma unroll
    for (int off = 32; off > 0; off >>= 1) ss += __shfl_down(ss, off, 64);
    if (lane == 0) nrm[row] = ss;

    unsigned short u[8];
    float vals[8] = {v0.x, v0.y, v0.z, v0.w, v1.x, v1.y, v1.z, v1.w};
#pragma unroll
    for (int e = 0; e < 8; ++e) u[e] = f32_to_bf16_rne(vals[e] * scale);
    unsigned int w0 = (unsigned)u[0] | ((unsigned)u[1] << 16);
    unsigned int w1 = (unsigned)u[2] | ((unsigned)u[3] << 16);
    unsigned int w2 = (unsigned)u[4] | ((unsigned)u[5] << 16);
    unsigned int w3 = (unsigned)u[6] | ((unsigned)u[7] << 16);
    uint4 pk = make_uint4(w0, w1, w2, w3);
    ((uint4*)(xb + (size_t)row * 512))[lane] = pk;
}

// Block: bm = bid>>2 (M-panel of 128 rows), qt = bid&3 (N-quarter).
// bid&7 = (bm&1)*4 + qt -> each XCD serves one N-quarter (per bm parity):
// B working set per XCD ~2 MB (L2-fit) + streamed A panels.
// Waves: 2x2 over 128M x 64N -> wave tile 64M x 32N.
//   acc[im 0..3][in 0..1], per K-tile(64): 8 A-frag + 4 B-frag ds_read_b128,
//   16 MFMA. A LDS: [128 rows][64 chunks], slot = chunk low3 ^ (row&7).
//   B LDS: 3 slots x [64 rows][8 chunks], slot = chunk ^ (row&7).
// Iter u = j*8 + t (j = B-tile, t = K-tile): { vmcnt(2|0); barrier;
// stage(u+2) -> ring slot (u+2)%3; ds_read tile u from slot u%3; 16 MFMA;
// t==7: fused epilogue stores for tile j }.

__global__ __launch_bounds__(256, 1) void dist_mfma(const unsigned short* __restrict__ sbuf,
                                                    const unsigned short* __restrict__ tbuf,
                                                    const float* __restrict__ ssq,
                                                    const float* __restrict__ tsq,
                                                    float* __restrict__ out,
                                                    int N, int Q, int D) {
    __shared__ __align__(16) unsigned short lds_a[128 * 512];   // 128 KB
    __shared__ __align__(16) unsigned short lds_b[3 * 64 * 64]; // 24 KB

    const int tid  = threadIdx.x;
    const int wid  = tid >> 6;
    const int lane = tid & 63;
    const int quad = lane >> 4;
    const int r    = lane & 15;
    const int m_w  = (wid & 1) * 64;
    const int n_w  = (wid >> 1) * 32;

    const int bm    = blockIdx.x >> 2;
    const int qt    = blockIdx.x & 3;
    const int gm0   = bm * 128;
    const int qcols = Q >> 2;              // 2048
    const int qbase = qt * qcols;
    const int jT    = qcols >> 6;          // 32 B-tiles of 64 cols
    const int uEnd  = jT * 8;              // 256

    // ---- A-panel staging: 32 instrs, one 1 KB row each (row = i*4 + wid).
#pragma unroll
    for (int i = 0; i < 32; ++i) {
        const int row = i * 4 + wid;
        const int gch = (lane & 56) | ((lane ^ row) & 7);
        async_load16(sbuf + (size_t)(gm0 + row) * 512 + gch * 8,
                     lds_a + (size_t)row * 512);
    }

    // ---- B staging invariants: instr i, row = i*32 + wid*8 + (lane>>3),
    // slot = lane&7, global chunk = slot ^ (row&7).
    const unsigned short* bInv[2];
    unsigned short* bDst[2];
#pragma unroll
    for (int i = 0; i < 2; ++i) {
        const int row = i * 32 + wid * 8 + (lane >> 3);
        const int gch = (lane & 7) ^ ((lane >> 3) & 7);
        bInv[i] = tbuf + (size_t)(qbase + row) * 512 + gch * 8;
        bDst[i] = lds_b + (i * 256 + wid * 64) * 8;
    }

#define STAGE_B(jn, tn, slot) do {                                            \
        async_load16(bInv[0] + (size_t)(jn) * 32768 + (tn) * 64,              \
                     bDst[0] + (slot) * 4096);                                \
        async_load16(bInv[1] + (size_t)(jn) * 32768 + (tn) * 64,              \
                     bDst[1] + (slot) * 4096);                                \
    } while (0)

    STAGE_B(0, 0, 0);
    STAGE_B(0, 1, 1);

    // ---- fragment read offsets (shorts); per K-tile t add t*64 for A.
    int aIdx[4][2], bIdx[2][2];
#pragma unroll
    for (int im = 0; im < 4; ++im) {
        const int row = m_w + im * 16 + r;
#pragma unroll
        for (int ks = 0; ks < 2; ++ks)
            aIdx[im][ks] = row * 512 + (((ks * 4 + quad) ^ (row & 7)) * 8);
    }
#pragma unroll
    for (int in = 0; in < 2; ++in) {
        const int row = n_w + in * 16 + r;
#pragma unroll
        for (int ks = 0; ks < 2; ++ks)
            bIdx[in][ks] = row * 64 + (((ks * 4 + quad) ^ (row & 7)) * 8);
    }

    f32x4 acc[4][2];
#pragma unroll
    for (int a = 0; a < 4; ++a)
#pragma unroll
        for (int b = 0; b < 2; ++b) acc[a][b] = (f32x4){0.f, 0.f, 0.f, 0.f};

    int scur = 0;  // ring slot of tile u

    for (int j = 0; j < jT; ++j) {
#pragma unroll
        for (int t = 0; t < 8; ++t) {
            const int u = j * 8 + t;
            // Certify tile u: drain all but the newest prefetch pair.
            // (Occasional outstanding epilogue stores get drained too —
            // that only paces us to the HBM-write floor.)
            if (u + 1 < uEnd) {
                asm volatile("s_waitcnt vmcnt(2)" ::: "memory");
            } else {
                asm volatile("s_waitcnt vmcnt(0)" ::: "memory");
            }
            __builtin_amdgcn_sched_barrier(0);
            __builtin_amdgcn_s_barrier();
            __builtin_amdgcn_sched_barrier(0);

            // Prefetch tile u+2 into slot (u+2)%3 (its last readers were
            // iter u-1, certified by the barrier above).
            if (u + 2 < uEnd) {
                const int un = u + 2;
                const int s2 = (scur >= 1) ? scur - 1 : scur + 2;
                STAGE_B(un >> 3, un & 7, s2);
            }

            const unsigned short* bb = lds_b + scur * 4096;
            short8v aF[4][2], bF[2][2];
#pragma unroll
            for (int im = 0; im < 4; ++im)
#pragma unroll
                for (int ks = 0; ks < 2; ++ks)
                    aF[im][ks] = *(const short8v*)(lds_a + aIdx[im][ks] + t * 64);
#pragma unroll
            for (int in = 0; in < 2; ++in)
#pragma unroll
                for (int ks = 0; ks < 2; ++ks)
                    bF[in][ks] = *(const short8v*)(bb + bIdx[in][ks]);
#pragma unroll
            for (int ks = 0; ks < 2; ++ks)
#pragma unroll
                for (int im = 0; im < 4; ++im)
#pragma unroll
                    for (int in = 0; in < 2; ++in)
                        acc[im][in] = __builtin_amdgcn_mfma_f32_16x16x32_bf16(
                            aF[im][ks], bF[in][ks], acc[im][in], 0, 0, 0);

            if (t == 7) {
                // fused epilogue for B-tile j; C/D layout col = lane&15,
                // row = quad*4 + reg. Nontemporal: don't evict the
                // L2/L3-resident inputs with the 268 MB output stream.
                const int gn = qbase + j * 64 + n_w;
                float tq[2];
#pragma unroll
                for (int in = 0; in < 2; ++in) tq[in] = tsq[gn + in * 16 + r];
#pragma unroll
                for (int im = 0; im < 4; ++im) {
#pragma unroll
                    for (int jj = 0; jj < 4; ++jj) {
                        const int i = gm0 + m_w + im * 16 + quad * 4 + jj;
                        const float sv = ssq[i];
                        float* orow = out + (size_t)i * (size_t)Q + gn;
#pragma unroll
                        for (int in = 0; in < 2; ++in)
                            __builtin_nontemporal_store(
                                sv + tq[in] + acc[im][in][jj],
                                &orow[in * 16 + r]);
                    }
                }
#pragma unroll
                for (int a = 0; a < 4; ++a)
#pragma unroll
                    for (int b = 0; b < 2; ++b)
                        acc[a][b] = (f32x4){0.f, 0.f, 0.f, 0.f};
            }
            scur = (scur == 2) ? 0 : scur + 1;
        }
    }
#undef STAGE_B
}

// Correctness fallback if d_ws is too small for the bf16 copies or shapes
// don't fit the tiled path.
__global__ void dist_fallback(const float* __restrict__ s, const float* __restrict__ t,
                              float* __restrict__ out, int N, int Q, int D) {
    __shared__ float ls[16][17], lt[16][17];
    const int tj = threadIdx.x, ti = threadIdx.y;
    const int i = blockIdx.y * 16 + ti, j = blockIdx.x * 16 + tj;
    float cross = 0.f, ssq = 0.f, tsq = 0.f;
    for (int k0 = 0; k0 < D; k0 += 16) {
        __syncthreads();
        ls[ti][tj] = s[(size_t)(blockIdx.y * 16 + ti) * D + k0 + tj];
        lt[ti][tj] = t[(size_t)(blockIdx.x * 16 + ti) * D + k0 + tj];
        __syncthreads();
#pragma unroll
        for (int kk = 0; kk < 16; ++kk) {
            float a = ls[ti][kk], b = lt[tj][kk];
            cross += a * b; ssq += a * a; tsq += b * b;
        }
    }
    out[(size_t)i * Q + j] = ssq + tsq - 2.f * cross;
}

extern "C" void kernel_launch(void* const* d_in, const int* in_sizes, int n_in,
                              void* d_out, int out_size, void* d_ws, size_t ws_size,
                              hipStream_t stream) {
    const float* s = (const float*)d_in[0];
    const float* t = (const float*)d_in[1];
    float* out = (float*)d_out;
    const int D = 512;
    const int N = in_sizes[0] / D;  // 8192
    const int Q = in_sizes[1] / D;  // 8192

    const size_t need = ((size_t)N + (size_t)Q) * D * sizeof(unsigned short)
                      + ((size_t)N + (size_t)Q) * sizeof(float);

    if (ws_size >= need && D == 512 && (N % 128) == 0 && (Q % 256) == 0) {
        unsigned short* sb = (unsigned short*)d_ws;
        unsigned short* tb = sb + (size_t)N * D;
        float* ssq = (float*)(tb + (size_t)Q * D);
        float* tsq = ssq + N;
        prep_kernel<<<N / 4, 256, 0, stream>>>(s, sb, ssq, -2.0f);
        prep_kernel<<<Q / 4, 256, 0, stream>>>(t, tb, tsq, 1.0f);
        const int blocks = (N / 128) * 4;
        dist_mfma<<<blocks, 256, 0, stream>>>(sb, tb, ssq, tsq, out, N, Q, D);
    } else {
        dim3 g(Q / 16, N / 16), b(16, 16);
        dist_fallback<<<g, b, 0, stream>>>(s, t, out, N, Q, D);
    }
}